// Round 1
// baseline (378.991 us; speedup 1.0000x reference)
//
#include <hip/hip_runtime.h>
#include <hip/hip_bf16.h>

// DiGCN forward, MI355X. B=8 S=1024 D=768 L=2.
// bf16 MFMA GEMMs (16x16x32), fp32 softmax/LN. fp32 in/out.

using bf16 = __hip_bfloat16;
typedef __attribute__((ext_vector_type(8))) short short8;   // 8 bf16 = 4 VGPR (MFMA A/B frag)
typedef __attribute__((ext_vector_type(4))) float f32x4;    // MFMA C/D frag

#define B_ 8
#define S_ 1024
#define D_ 768
#define BS_ 8192
#define SS_ 1048576L
#define SD_ 786432L
#define DD_ 589824L

__device__ __forceinline__ void gload16(const void* g, void* l) {
  __builtin_amdgcn_global_load_lds((const __attribute__((address_space(1))) void*)g,
                                   (__attribute__((address_space(3))) void*)l, 16, 0, 0);
}

__device__ __forceinline__ f32x4 mfma16(short8 a, short8 b, f32x4 c) {
  return __builtin_amdgcn_mfma_f32_16x16x32_bf16(a, b, c, 0, 0, 0);
}

__device__ __forceinline__ float wave_sum(float v) {
  #pragma unroll
  for (int o = 32; o; o >>= 1) v += __shfl_xor(v, o);
  return v;
}
__device__ __forceinline__ float wave_max(float v) {
  #pragma unroll
  for (int o = 32; o; o >>= 1) v = fmaxf(v, __shfl_xor(v, o));
  return v;
}

// ---- GEMM core: C(128x128) += A(128xK) * B(128xK)^T, K in 64-wide tiles ----
// LDS tile [128 rows][64 bf16], XOR-swizzled: chunk slot = chunk ^ (row&7).
// Staged via global_load_lds (linear dest, pre-swizzled global source).
__device__ __forceinline__ void stage_tile(const bf16* g, long ld, int kt, short* s,
                                           int w, int lane) {
  #pragma unroll
  for (int i = 0; i < 4; ++i) {
    int rt = w * 32 + i * 8 + (lane >> 3);       // row within tile
    int ch = lane & 7;                            // 16B chunk slot within row
    const bf16* src = g + (long)rt * ld + (long)kt * 64 + ((ch ^ (rt & 7)) << 3);
    gload16((const void*)src, (void*)(s + (w * 32 + i * 8) * 64));
  }
}

__device__ __forceinline__ short8 read_frag(const short* s, int r0, int kk, int lane) {
  int r = r0 + (lane & 15);
  int c = (kk << 2) + (lane >> 4);                // 16B chunk index wanted
  return *(const short8*)((const char*)s + r * 128 + ((c ^ (r & 7)) << 4));
}

__device__ __forceinline__ void gemm_loop(const bf16* A, long lda, const bf16* Bm, long ldb,
                                          int kt0, int kt1, short* As, short* Bs,
                                          f32x4 acc[4][4], int w, int lane, int wm, int wn) {
  for (int kt = kt0; kt < kt1; ++kt) {
    __syncthreads();                              // LDS free (prev compute done)
    stage_tile(A, lda, kt, As, w, lane);
    stage_tile(Bm, ldb, kt, Bs, w, lane);
    __syncthreads();                              // staging complete (vmcnt drained)
    #pragma unroll
    for (int kk = 0; kk < 2; ++kk) {
      short8 af[4], bfr[4];
      #pragma unroll
      for (int m = 0; m < 4; ++m) af[m] = read_frag(As, wm * 64 + m * 16, kk, lane);
      #pragma unroll
      for (int n = 0; n < 4; ++n) bfr[n] = read_frag(Bs, wn * 64 + n * 16, kk, lane);
      #pragma unroll
      for (int m = 0; m < 4; ++m)
        #pragma unroll
        for (int n = 0; n < 4; ++n)
          acc[m][n] = mfma16(af[m], bfr[n], acc[m][n]);
    }
  }
}

// ---- scores = scale * hb @ hb^T  (batched) ----
__global__ __launch_bounds__(256) void k_scores(const bf16* __restrict__ hb,
                                                float* __restrict__ out, float scale) {
  __shared__ short As[128 * 64], Bs[128 * 64];
  int b = blockIdx.z;
  int tid = threadIdx.x, w = tid >> 6, lane = tid & 63, wm = w >> 1, wn = w & 1;
  const bf16* A = hb + (long)b * SD_ + (long)blockIdx.x * 128 * D_;
  const bf16* Bp = hb + (long)b * SD_ + (long)blockIdx.y * 128 * D_;
  f32x4 acc[4][4] = {};
  gemm_loop(A, D_, Bp, D_, 0, 12, As, Bs, acc, w, lane, wm, wn);
  float* C = out + (long)b * SS_;
  int row0 = blockIdx.x * 128 + wm * 64, col0 = blockIdx.y * 128 + wn * 64;
  #pragma unroll
  for (int m = 0; m < 4; ++m) {
    int r = row0 + m * 16 + ((lane >> 4) << 2);
    #pragma unroll
    for (int n = 0; n < 4; ++n) {
      int c = col0 + n * 16 + (lane & 15);
      #pragma unroll
      for (int j = 0; j < 4; ++j) C[(long)(r + j) * S_ + c] = acc[m][n][j] * scale;
    }
  }
}

// ---- hl/hs/hr = hb @ W^T + bias; z=0->hlT (transposed), z=1->hs, z=2->hrT ----
__global__ __launch_bounds__(256) void k_proj(const bf16* __restrict__ hb,
                                              const bf16* __restrict__ Wb,
                                              const float* __restrict__ bl,
                                              const float* __restrict__ bs,
                                              const float* __restrict__ br,
                                              bf16* __restrict__ hlT,
                                              bf16* __restrict__ hsb,
                                              bf16* __restrict__ hrT) {
  __shared__ short As[128 * 64], Bs[128 * 64];
  int z = blockIdx.z;
  int tid = threadIdx.x, w = tid >> 6, lane = tid & 63, wm = w >> 1, wn = w & 1;
  const bf16* A = hb + (long)blockIdx.x * 128 * D_;
  const bf16* Bp = Wb + (long)z * DD_ + (long)blockIdx.y * 128 * D_;
  f32x4 acc[4][4] = {};
  gemm_loop(A, D_, Bp, D_, 0, 12, As, Bs, acc, w, lane, wm, wn);
  const float* bias = (z == 0) ? bl : (z == 1) ? bs : br;
  int row0 = blockIdx.x * 128 + wm * 64, col0 = blockIdx.y * 128 + wn * 64;
  if (z == 1) {
    #pragma unroll
    for (int m = 0; m < 4; ++m) {
      int r = row0 + m * 16 + ((lane >> 4) << 2);
      #pragma unroll
      for (int n = 0; n < 4; ++n) {
        int c = col0 + n * 16 + (lane & 15);
        float bv = bias[c];
        #pragma unroll
        for (int j = 0; j < 4; ++j)
          hsb[(long)(r + j) * D_ + c] = __float2bfloat16(acc[m][n][j] + bv);
      }
    }
  } else {
    bf16* outT = (z == 0) ? hlT : hrT;
    #pragma unroll
    for (int m = 0; m < 4; ++m) {
      int r = row0 + m * 16 + ((lane >> 4) << 2);
      #pragma unroll
      for (int n = 0; n < 4; ++n) {
        int c = col0 + n * 16 + (lane & 15);
        float bv = bias[c];
        #pragma unroll
        for (int j = 0; j < 4; ++j)
          outT[(long)c * BS_ + r + j] = __float2bfloat16(acc[m][n][j] + bv);
      }
    }
  }
}

// ---- softmax + adjacency renorm; split into strict-upper/lower bf16 + diag ----
__global__ __launch_bounds__(256) void k_softmax(const float* __restrict__ scores,
                                                 const float* __restrict__ adj,
                                                 bf16* __restrict__ attnU,
                                                 bf16* __restrict__ attnL,
                                                 float* __restrict__ diag) {
  int wv = threadIdx.x >> 6, lane = threadIdx.x & 63;
  int row = blockIdx.x * 4 + wv;                  // 0..8191 (= b*1024 + i)
  int i = row & (S_ - 1);
  const float* srow = scores + (long)row * S_;
  const float* arow = adj + (long)row * S_;
  float s[16], a[16], p[16];
  #pragma unroll
  for (int k = 0; k < 16; ++k) { int idx = k * 64 + lane; s[k] = srow[idx]; a[k] = arow[idx]; }
  float mx = -1e30f;
  #pragma unroll
  for (int k = 0; k < 16; ++k) mx = fmaxf(mx, s[k]);
  mx = wave_max(mx);
  float Z = 0.f, Sm = 0.f;
  #pragma unroll
  for (int k = 0; k < 16; ++k) { p[k] = __expf(s[k] - mx); Z += p[k]; Sm += p[k] * a[k]; }
  Z = wave_sum(Z); Sm = wave_sum(Sm);
  float inv = 1.0f / (Sm + 1e-10f * Z);           // softmax Z cancels algebraically
  #pragma unroll
  for (int k = 0; k < 16; ++k) {
    int j = k * 64 + lane;
    float at = p[k] * a[k] * inv;
    attnU[(long)row * S_ + j] = __float2bfloat16(j > i ? at : 0.f);
    attnL[(long)row * S_ + j] = __float2bfloat16(j < i ? at : 0.f);
    if (j == i) diag[row] = at;
  }
}

// ---- ctx = attnU@hl + attnL@hr + diag*hs  (batched, triangular K-skip) ----
__global__ __launch_bounds__(256) void k_ctx(const bf16* __restrict__ attnU,
                                             const bf16* __restrict__ attnL,
                                             const bf16* __restrict__ hlT,
                                             const bf16* __restrict__ hrT,
                                             const bf16* __restrict__ hsb,
                                             const float* __restrict__ diag,
                                             float* __restrict__ ctx) {
  __shared__ short As[128 * 64], Bs[128 * 64];
  int b = blockIdx.z;
  int tid = threadIdx.x, w = tid >> 6, lane = tid & 63, wm = w >> 1, wn = w & 1;
  int rm = blockIdx.x * 128;
  int t = rm >> 6;                                 // first upper K-tile
  const bf16* A1 = attnU + (long)b * SS_ + (long)rm * S_;
  const bf16* B1 = hlT + (long)blockIdx.y * 128 * BS_ + (long)b * S_;
  const bf16* A2 = attnL + (long)b * SS_ + (long)rm * S_;
  const bf16* B2 = hrT + (long)blockIdx.y * 128 * BS_ + (long)b * S_;
  f32x4 acc[4][4] = {};
  gemm_loop(A1, S_, B1, BS_, t, 16, As, Bs, acc, w, lane, wm, wn);     // j > i
  gemm_loop(A2, S_, B2, BS_, 0, t + 2, As, Bs, acc, w, lane, wm, wn);  // j < i
  int row0 = rm + wm * 64, col0 = blockIdx.y * 128 + wn * 64;
  #pragma unroll
  for (int m = 0; m < 4; ++m) {
    int r = row0 + m * 16 + ((lane >> 4) << 2);
    float dg[4];
    #pragma unroll
    for (int j = 0; j < 4; ++j) dg[j] = diag[b * S_ + r + j];
    #pragma unroll
    for (int n = 0; n < 4; ++n) {
      int c = col0 + n * 16 + (lane & 15);
      #pragma unroll
      for (int j = 0; j < 4; ++j) {
        long gr = (long)(b * S_ + r + j);
        float hv = __bfloat162float(hsb[gr * D_ + c]);
        ctx[gr * D_ + c] = acc[m][n][j] + dg[j] * hv;
      }
    }
  }
}

// ---- LayerNorm + ReLU; writes fp32 d_out (last layer) or bf16 hb (next layer) ----
__global__ __launch_bounds__(256) void k_ln(const float* __restrict__ ctx,
                                            const float* __restrict__ g,
                                            const float* __restrict__ beta,
                                            float* __restrict__ outF,
                                            bf16* __restrict__ outB) {
  int wv = threadIdx.x >> 6, lane = threadIdx.x & 63;
  long row = (long)blockIdx.x * 4 + wv;
  const float* x = ctx + row * D_;
  float v[12]; float s = 0.f;
  #pragma unroll
  for (int k = 0; k < 12; ++k) { v[k] = x[k * 64 + lane]; s += v[k]; }
  s = wave_sum(s);
  float mean = s * (1.0f / 768.0f);
  float q = 0.f;
  #pragma unroll
  for (int k = 0; k < 12; ++k) { float d = v[k] - mean; q += d * d; }
  q = wave_sum(q);
  float inv = rsqrtf(fmaxf(q * (1.0f / 768.0f), 0.f) + 1e-12f);
  #pragma unroll
  for (int k = 0; k < 12; ++k) {
    int c = k * 64 + lane;
    float o = fmaxf((v[k] - mean) * inv * g[c] + beta[c], 0.f);
    if (outF) outF[row * D_ + c] = o;
    if (outB) outB[row * D_ + c] = __float2bfloat16(o);
  }
}

// ---- fp32 -> bf16 casts ----
__global__ __launch_bounds__(256) void k_castf(const float* __restrict__ in,
                                               bf16* __restrict__ out) {
  long idx = ((long)blockIdx.x * 256 + threadIdx.x) * 4;
  float4 f = *(const float4*)(in + idx);
  out[idx] = __float2bfloat16(f.x);
  out[idx + 1] = __float2bfloat16(f.y);
  out[idx + 2] = __float2bfloat16(f.z);
  out[idx + 3] = __float2bfloat16(f.w);
}

__global__ __launch_bounds__(256) void k_castw(const float* __restrict__ wl,
                                               const float* __restrict__ ws_,
                                               const float* __restrict__ wr,
                                               bf16* __restrict__ out) {
  const float* src = (blockIdx.y == 0) ? wl : (blockIdx.y == 1) ? ws_ : wr;
  bf16* o = out + (long)blockIdx.y * DD_;
  long idx = ((long)blockIdx.x * 256 + threadIdx.x) * 4;
  float4 f = *(const float4*)(src + idx);
  o[idx] = __float2bfloat16(f.x);
  o[idx + 1] = __float2bfloat16(f.y);
  o[idx + 2] = __float2bfloat16(f.z);
  o[idx + 3] = __float2bfloat16(f.w);
}

extern "C" void kernel_launch(void* const* d_in, const int* in_sizes, int n_in,
                              void* d_out, int out_size, void* d_ws, size_t ws_size,
                              hipStream_t stream) {
  const float* hidden = (const float*)d_in[0];
  const float* adj    = (const float*)d_in[1];
  const float* Wl     = (const float*)d_in[2];
  const float* bl     = (const float*)d_in[3];
  const float* Ws     = (const float*)d_in[4];
  const float* bs     = (const float*)d_in[5];
  const float* Wr     = (const float*)d_in[6];
  const float* br     = (const float*)d_in[7];
  const float* lnw    = (const float*)d_in[8];
  const float* lnb    = (const float*)d_in[9];
  float* out = (float*)d_out;

  char* ws = (char*)d_ws;
  bf16*  hb    = (bf16*)(ws);                    // 12,582,912 B
  bf16*  hlT   = (bf16*)(ws + 12582912);         // [768][8192]
  bf16*  hrT   = (bf16*)(ws + 25165824);
  bf16*  hsb   = (bf16*)(ws + 37748736);         // [8192][768]
  bf16*  Wb    = (bf16*)(ws + 50331648);         // 3 x 768^2
  float* diag  = (float*)(ws + 53870592);        // 8192 floats
  bf16*  attnU = (bf16*)(ws + 53903360);         // [8][1024][1024]
  bf16*  attnL = (bf16*)(ws + 70680576);
  float* scores = (float*)(ws + 87457792);       // fp32 [8][1024][1024]
  float* ctx = scores;                           // disjoint lifetime -> alias

  const float scale = 0.03608439182435161f;      // 1/sqrt(768)

  k_castf<<<6144, 256, 0, stream>>>(hidden, hb);
  for (int l = 0; l < 2; ++l) {
    long wo = (long)l * DD_;
    k_castw<<<dim3(576, 3), 256, 0, stream>>>(Wl + wo, Ws + wo, Wr + wo, Wb);
    k_scores<<<dim3(8, 8, B_), 256, 0, stream>>>(hb, scores, scale);
    k_softmax<<<2048, 256, 0, stream>>>(scores, adj, attnU, attnL, diag);
    k_proj<<<dim3(64, 6, 3), 256, 0, stream>>>(hb, Wb, bl + l * D_, bs + l * D_,
                                               br + l * D_, hlT, hsb, hrT);
    k_ctx<<<dim3(8, 6, B_), 256, 0, stream>>>(attnU, attnL, hlT, hrT, hsb, diag, ctx);
    k_ln<<<2048, 256, 0, stream>>>(ctx, lnw + l * D_, lnb + l * D_,
                                   (l == 1) ? out : nullptr,
                                   (l == 1) ? (bf16*)nullptr : hb);
  }
}

// Round 3
// 351.478 us; speedup vs baseline: 1.0783x; 1.0783x over previous
//
#include <hip/hip_runtime.h>
#include <hip/hip_bf16.h>

// DiGCN forward, MI355X. B=8 S=1024 D=768 L=2.
// bf16 MFMA GEMMs (16x16x32) with 2-phase LDS double-buffer (T3-minimum),
// softmax fused into scores epilogue (normalizer applied in ctx epilogue).

using bf16 = __hip_bfloat16;
typedef __attribute__((ext_vector_type(8))) short short8;   // 8 bf16 = 4 VGPR
typedef __attribute__((ext_vector_type(4))) float f32x4;    // MFMA C/D frag

#define B_ 8
#define S_ 1024
#define D_ 768
#define BS_ 8192
#define SS_ 1048576L
#define SD_ 786432L
#define DD_ 589824L

__device__ __forceinline__ void gload16(const void* g, void* l) {
  __builtin_amdgcn_global_load_lds((const __attribute__((address_space(1))) void*)g,
                                   (__attribute__((address_space(3))) void*)l, 16, 0, 0);
}

__device__ __forceinline__ f32x4 mfma16(short8 a, short8 b, f32x4 c) {
  return __builtin_amdgcn_mfma_f32_16x16x32_bf16(a, b, c, 0, 0, 0);
}

__device__ __forceinline__ float wave_sum(float v) {
  #pragma unroll
  for (int o = 32; o; o >>= 1) v += __shfl_xor(v, o);
  return v;
}

// ---- LDS tile [128 rows][64 bf16], XOR-swizzled: chunk slot = chunk ^ (row&7).
// Staged via global_load_lds (linear dest, pre-swizzled global source, rule #21).
__device__ __forceinline__ void stage_tile(const bf16* g, long ld, int kt, short* s,
                                           int w, int lane) {
  #pragma unroll
  for (int i = 0; i < 4; ++i) {
    int rt = w * 32 + i * 8 + (lane >> 3);        // row within tile
    int ch = lane & 7;                            // 16B chunk slot within row
    const bf16* src = g + (long)rt * ld + (long)kt * 64 + ((ch ^ (rt & 7)) << 3);
    gload16((const void*)src, (void*)(s + (w * 32 + i * 8) * 64));
  }
}

__device__ __forceinline__ short8 read_frag(const short* s, int r0, int kk, int lane) {
  int r = r0 + (lane & 15);
  int c = (kk << 2) + (lane >> 4);                // 16B chunk index wanted
  return *(const short8*)((const char*)s + r * 128 + ((c ^ (r & 7)) << 4));
}

__device__ __forceinline__ void compute_tile(const short* As, const short* Bs,
                                             f32x4 acc[4][4], int lane, int wm, int wn) {
  #pragma unroll
  for (int kk = 0; kk < 2; ++kk) {
    short8 af[4], bfr[4];
    #pragma unroll
    for (int m = 0; m < 4; ++m) af[m] = read_frag(As, wm * 64 + m * 16, kk, lane);
    #pragma unroll
    for (int n = 0; n < 4; ++n) bfr[n] = read_frag(Bs, wn * 64 + n * 16, kk, lane);
    #pragma unroll
    for (int m = 0; m < 4; ++m)
      #pragma unroll
      for (int n = 0; n < 4; ++n)
        acc[m][n] = mfma16(af[m], bfr[n], acc[m][n]);
  }
}

// 2-phase double-buffered GEMM loop (T3-minimum): single A/B source pair.
__device__ __forceinline__ void gemm_db(const bf16* A, long lda, const bf16* Bm, long ldb,
                                        int kt0, int kt1, short (*L)[8192],
                                        f32x4 acc[4][4], int w, int lane, int wm, int wn) {
  stage_tile(A, lda, kt0, L[0], w, lane);
  stage_tile(Bm, ldb, kt0, L[1], w, lane);
  asm volatile("s_waitcnt vmcnt(0)");
  __syncthreads();
  int cur = 0;
  for (int kt = kt0; kt < kt1; ++kt) {
    if (kt + 1 < kt1) {
      stage_tile(A, lda, kt + 1, L[2 * (cur ^ 1)], w, lane);
      stage_tile(Bm, ldb, kt + 1, L[2 * (cur ^ 1) + 1], w, lane);
    }
    compute_tile(L[2 * cur], L[2 * cur + 1], acc, lane, wm, wn);
    asm volatile("s_waitcnt vmcnt(0)");
    __syncthreads();
    cur ^= 1;
  }
}

// ---- scores GEMM + fused exp/adj-mask epilogue ----
// pa = exp(scale*u)*adj (bf16) split strict-upper/lower + diag; row sums via atomics.
__global__ __launch_bounds__(256) void k_scores(const bf16* __restrict__ hb,
                                                const float* __restrict__ adj,
                                                bf16* __restrict__ paU,
                                                bf16* __restrict__ paL,
                                                float* __restrict__ diagpa,
                                                float* __restrict__ Sm,
                                                float* __restrict__ Zs,
                                                float scale) {
  __shared__ short L[4][8192];
  int b = blockIdx.z;
  int tid = threadIdx.x, w = tid >> 6, lane = tid & 63, wm = w >> 1, wn = w & 1;
  const bf16* A = hb + (long)b * SD_ + (long)blockIdx.x * 128 * D_;
  const bf16* Bp = hb + (long)b * SD_ + (long)blockIdx.y * 128 * D_;
  f32x4 acc[4][4] = {};
  gemm_db(A, D_, Bp, D_, 0, 12, L, acc, w, lane, wm, wn);
  int row0 = blockIdx.x * 128 + wm * 64, col0 = blockIdx.y * 128 + wn * 64;
  #pragma unroll
  for (int m = 0; m < 4; ++m) {
    int rbase = row0 + m * 16 + ((lane >> 4) << 2);
    #pragma unroll
    for (int j = 0; j < 4; ++j) {
      int rs = rbase + j;                          // row within batch (0..1023)
      long rowg = (long)b * S_ + rs;
      float psum = 0.f, pasum = 0.f;
      #pragma unroll
      for (int n = 0; n < 4; ++n) {
        int cs = col0 + n * 16 + (lane & 15);
        float p = __expf(acc[m][n][j] * scale);    // no max-sub: u bounded (<~35)
        float a = adj[rowg * S_ + cs];
        bf16 pb = __float2bfloat16(p * a);
        float pa = __bfloat162float(pb);           // sum the rounded value
        psum += p; pasum += pa;
        paU[rowg * S_ + cs] = (cs > rs) ? pb : __float2bfloat16(0.f);
        paL[rowg * S_ + cs] = (cs < rs) ? pb : __float2bfloat16(0.f);
        if (cs == rs) diagpa[rowg] = pa;
      }
      #pragma unroll
      for (int o = 1; o < 16; o <<= 1) {
        psum += __shfl_xor(psum, o);
        pasum += __shfl_xor(pasum, o);
      }
      if ((lane & 15) == 0) {
        atomicAdd(&Sm[rowg], pasum);
        atomicAdd(&Zs[rowg], psum);
      }
    }
  }
}

// ---- hl/hs/hr = hb @ W^T + bias; z=0->hlT (transposed), z=1->hs, z=2->hrT ----
__global__ __launch_bounds__(256) void k_proj(const bf16* __restrict__ hb,
                                              const bf16* __restrict__ Wb,
                                              const float* __restrict__ bl,
                                              const float* __restrict__ bs,
                                              const float* __restrict__ br,
                                              bf16* __restrict__ hlT,
                                              bf16* __restrict__ hsb,
                                              bf16* __restrict__ hrT) {
  __shared__ short L[4][8192];
  int z = blockIdx.z;
  int tid = threadIdx.x, w = tid >> 6, lane = tid & 63, wm = w >> 1, wn = w & 1;
  const bf16* A = hb + (long)blockIdx.x * 128 * D_;
  const bf16* Bp = Wb + (long)z * 2 * DD_ + (long)blockIdx.y * 128 * D_;
  f32x4 acc[4][4] = {};
  gemm_db(A, D_, Bp, D_, 0, 12, L, acc, w, lane, wm, wn);
  const float* bias = (z == 0) ? bl : (z == 1) ? bs : br;
  int row0 = blockIdx.x * 128 + wm * 64, col0 = blockIdx.y * 128 + wn * 64;
  if (z == 1) {
    #pragma unroll
    for (int m = 0; m < 4; ++m) {
      int r = row0 + m * 16 + ((lane >> 4) << 2);
      #pragma unroll
      for (int n = 0; n < 4; ++n) {
        int c = col0 + n * 16 + (lane & 15);
        float bv = bias[c];
        #pragma unroll
        for (int j = 0; j < 4; ++j)
          hsb[(long)(r + j) * D_ + c] = __float2bfloat16(acc[m][n][j] + bv);
      }
    }
  } else {
    bf16* outT = (z == 0) ? hlT : hrT;
    #pragma unroll
    for (int m = 0; m < 4; ++m) {
      int r = row0 + m * 16 + ((lane >> 4) << 2);
      #pragma unroll
      for (int n = 0; n < 4; ++n) {
        int c = col0 + n * 16 + (lane & 15);
        float bv = bias[c];
        #pragma unroll
        for (int j = 0; j < 4; ++j)
          outT[(long)c * BS_ + r + j] = __float2bfloat16(acc[m][n][j] + bv);
      }
    }
  }
}

// ---- ctx = (paU@hl + paL@hr + diagpa*hs) * inv_row  (triangular K-skip) ----
__global__ __launch_bounds__(256) void k_ctx(const bf16* __restrict__ paU,
                                             const bf16* __restrict__ paL,
                                             const bf16* __restrict__ hlT,
                                             const bf16* __restrict__ hrT,
                                             const bf16* __restrict__ hsb,
                                             const float* __restrict__ diagpa,
                                             const float* __restrict__ Sm,
                                             const float* __restrict__ Zs,
                                             float* __restrict__ ctx) {
  __shared__ short L[4][8192];
  int b = blockIdx.z;
  int tid = threadIdx.x, w = tid >> 6, lane = tid & 63, wm = w >> 1, wn = w & 1;
  int rm = blockIdx.x * 128;
  int t = rm >> 6;                                 // first strictly-upper K-tile
  const bf16* A1 = paU + (long)b * SS_ + (long)rm * S_;
  const bf16* B1 = hlT + (long)blockIdx.y * 128 * BS_ + (long)b * S_;
  const bf16* A2 = paL + (long)b * SS_ + (long)rm * S_;
  const bf16* B2 = hrT + (long)blockIdx.y * 128 * BS_ + (long)b * S_;
  int ntU = 16 - t;                                // upper tiles: kt = t..15
  int nt = ntU + t + 2;                            // lower tiles: kt = 0..t+1
  f32x4 acc[4][4] = {};

  // unified 2-phase dbuf loop over the merged tile list
  const bf16 *Ap, *Bp; int kt;
  {
    Ap = A1; Bp = B1; kt = t;                      // q = 0 (ntU >= 2 always)
    stage_tile(Ap, S_, kt, L[0], w, lane);
    stage_tile(Bp, BS_, kt, L[1], w, lane);
  }
  asm volatile("s_waitcnt vmcnt(0)");
  __syncthreads();
  int cur = 0;
  for (int q = 0; q < nt; ++q) {
    if (q + 1 < nt) {
      int qn = q + 1;
      if (qn < ntU) { Ap = A1; Bp = B1; kt = t + qn; }
      else          { Ap = A2; Bp = B2; kt = qn - ntU; }
      stage_tile(Ap, S_, kt, L[2 * (cur ^ 1)], w, lane);
      stage_tile(Bp, BS_, kt, L[2 * (cur ^ 1) + 1], w, lane);
    }
    compute_tile(L[2 * cur], L[2 * cur + 1], acc, lane, wm, wn);
    asm volatile("s_waitcnt vmcnt(0)");
    __syncthreads();
    cur ^= 1;
  }

  int row0 = rm + wm * 64, col0 = blockIdx.y * 128 + wn * 64;
  #pragma unroll
  for (int m = 0; m < 4; ++m) {
    int r = row0 + m * 16 + ((lane >> 4) << 2);
    float dg[4], inv[4];
    #pragma unroll
    for (int j = 0; j < 4; ++j) {
      long gr = (long)b * S_ + r + j;
      dg[j] = diagpa[gr];
      inv[j] = 1.0f / (Sm[gr] + 1e-10f * Zs[gr]);
    }
    #pragma unroll
    for (int n = 0; n < 4; ++n) {
      int c = col0 + n * 16 + (lane & 15);
      #pragma unroll
      for (int j = 0; j < 4; ++j) {
        long gr = (long)b * S_ + r + j;
        float hv = __bfloat162float(hsb[gr * D_ + c]);
        ctx[gr * D_ + c] = (acc[m][n][j] + dg[j] * hv) * inv[j];
      }
    }
  }
}

// ---- LayerNorm + ReLU ----
__global__ __launch_bounds__(256) void k_ln(const float* __restrict__ ctx,
                                            const float* __restrict__ g,
                                            const float* __restrict__ beta,
                                            float* __restrict__ outF,
                                            bf16* __restrict__ outB) {
  int wv = threadIdx.x >> 6, lane = threadIdx.x & 63;
  long row = (long)blockIdx.x * 4 + wv;
  const float* x = ctx + row * D_;
  float v[12]; float s = 0.f;
  #pragma unroll
  for (int k = 0; k < 12; ++k) { v[k] = x[k * 64 + lane]; s += v[k]; }
  s = wave_sum(s);
  float mean = s * (1.0f / 768.0f);
  float q = 0.f;
  #pragma unroll
  for (int k = 0; k < 12; ++k) { float d = v[k] - mean; q += d * d; }
  q = wave_sum(q);
  float inv = rsqrtf(fmaxf(q * (1.0f / 768.0f), 0.f) + 1e-12f);
  #pragma unroll
  for (int k = 0; k < 12; ++k) {
    int c = k * 64 + lane;
    float o = fmaxf((v[k] - mean) * inv * g[c] + beta[c], 0.f);
    if (outF) outF[row * D_ + c] = o;
    if (outB) outB[row * D_ + c] = __float2bfloat16(o);
  }
}

// ---- fp32 -> bf16 casts ----
__global__ __launch_bounds__(256) void k_castf(const float* __restrict__ in,
                                               bf16* __restrict__ out) {
  long idx = ((long)blockIdx.x * 256 + threadIdx.x) * 4;
  float4 f = *(const float4*)(in + idx);
  out[idx] = __float2bfloat16(f.x);
  out[idx + 1] = __float2bfloat16(f.y);
  out[idx + 2] = __float2bfloat16(f.z);
  out[idx + 3] = __float2bfloat16(f.w);
}

// cast all weights for both layers once: out layout [z][l][D][D]
__global__ __launch_bounds__(256) void k_castw(const float* __restrict__ wl,
                                               const float* __restrict__ ws_,
                                               const float* __restrict__ wr,
                                               bf16* __restrict__ out) {
  const float* src = (blockIdx.y == 0) ? wl : (blockIdx.y == 1) ? ws_ : wr;
  bf16* o = out + (long)blockIdx.y * 2 * DD_;      // [z][l=0..1][..]
  long idx = ((long)blockIdx.x * 256 + threadIdx.x) * 4;
  float4 f = *(const float4*)(src + idx);
  o[idx] = __float2bfloat16(f.x);
  o[idx + 1] = __float2bfloat16(f.y);
  o[idx + 2] = __float2bfloat16(f.z);
  o[idx + 3] = __float2bfloat16(f.w);
}

extern "C" void kernel_launch(void* const* d_in, const int* in_sizes, int n_in,
                              void* d_out, int out_size, void* d_ws, size_t ws_size,
                              hipStream_t stream) {
  const float* hidden = (const float*)d_in[0];
  const float* adj    = (const float*)d_in[1];
  const float* Wl     = (const float*)d_in[2];
  const float* bl     = (const float*)d_in[3];
  const float* Ws     = (const float*)d_in[4];
  const float* bs     = (const float*)d_in[5];
  const float* Wr     = (const float*)d_in[6];
  const float* br     = (const float*)d_in[7];
  const float* lnw    = (const float*)d_in[8];
  const float* lnb    = (const float*)d_in[9];
  float* out = (float*)d_out;

  char* ws = (char*)d_ws;
  bf16*  hb     = (bf16*)(ws);                   // 12,582,912 B
  bf16*  hlT    = (bf16*)(ws + 12582912);        // [768][8192]
  bf16*  hrT    = (bf16*)(ws + 25165824);
  bf16*  hsb    = (bf16*)(ws + 37748736);        // [8192][768]
  bf16*  Wb     = (bf16*)(ws + 50331648);        // [3][2][768][768] = 7,077,888 B
  float* diagpa = (float*)(ws + 57409536);       // 8192 floats
  float* SmZ    = (float*)(ws + 57442304);       // Sm[8192] | Z[8192]
  bf16*  paU    = (bf16*)(ws + 57507840);        // [8][1024][1024]
  bf16*  paL    = (bf16*)(ws + 74285056);
  float* ctx    = (float*)(ws + 91062272);       // [8192][768] fp32 (+25.2 MB)

  float* Sm = SmZ;
  float* Zs = SmZ + BS_;
  const float scale = 0.03608439182435161f;      // 1/sqrt(768)

  k_castf<<<6144, 256, 0, stream>>>(hidden, hb);
  k_castw<<<dim3(1152, 3), 256, 0, stream>>>(Wl, Ws, Wr, Wb);
  for (int l = 0; l < 2; ++l) {
    hipMemsetAsync(SmZ, 0, 2 * BS_ * sizeof(float), stream);
    k_scores<<<dim3(8, 8, B_), 256, 0, stream>>>(hb, adj, paU, paL, diagpa, Sm, Zs, scale);
    k_proj<<<dim3(64, 6, 3), 256, 0, stream>>>(hb, Wb + (long)l * DD_, bl + l * D_,
                                               bs + l * D_, br + l * D_, hlT, hsb, hrT);
    k_ctx<<<dim3(8, 6, B_), 256, 0, stream>>>(paU, paL, hlT, hrT, hsb, diagpa, Sm, Zs, ctx);
    k_ln<<<2048, 256, 0, stream>>>(ctx, lnw + l * D_, lnb + l * D_,
                                   (l == 1) ? out : nullptr,
                                   (l == 1) ? (bf16*)nullptr : hb);
  }
}